// Round 17
// baseline (930.546 us; speedup 1.0000x reference)
//
#include <hip/hip_runtime.h>

#define NN 10000
#define NE 160000
#define DD 256
#define LEPS 1e-5f

typedef __attribute__((ext_vector_type(8))) short short8v;
typedef __attribute__((ext_vector_type(4))) float floatx4;
typedef unsigned short US;

static __device__ __forceinline__ US f2bf(float f){
  unsigned u = __builtin_bit_cast(unsigned, f);
  u += 0x7FFFu + ((u >> 16) & 1u);
  return (US)(u >> 16);
}
static __device__ __forceinline__ float bf2f(US s){
  unsigned u = ((unsigned)s) << 16;
  return __builtin_bit_cast(float, u);
}
template<typename T>
static __device__ __forceinline__ void ld8(const T* p, float* o){
  if constexpr (sizeof(T) == 2) {
    union { US h[8]; uint4 q; } u;
    u.q = *(const uint4*)p;
#pragma unroll
    for (int j = 0; j < 8; ++j) o[j] = bf2f(u.h[j]);
  } else {
    float4 a = *(const float4*)p; float4 b = *(const float4*)(p + 4);
    o[0]=a.x; o[1]=a.y; o[2]=a.z; o[3]=a.w; o[4]=b.x; o[5]=b.y; o[6]=b.z; o[7]=b.w;
  }
}
template<typename OT>
static __device__ __forceinline__ void st1(OT* p, float v){
  if constexpr (sizeof(OT) == 2) *p = (OT)f2bf(v); else *p = (OT)v;
}
static __device__ __forceinline__ uint4 pack8(const float* a){
  union { US h[8]; uint4 q; } pk;
#pragma unroll
  for (int j = 0; j < 8; ++j) pk.h[j] = f2bf(a[j]);
  return pk.q;
}

// ---- pack ALL layer weights into fragment-ready arena (kb-blocks of 2048 US)
#define AOFF_Q  0
#define AOFF_K1 (32*2048)
#define AOFF_K2 (64*2048)
#define AOFF_V1 (96*2048)
#define AOFF_V2 (128*2048)
#define AOFF_W  (160*2048)
#define AOFF_E1 (224*2048)
#define AOFF_E2 (256*2048)
#define AOFF_E3 (288*2048)
__global__ void pack_all_k(const float* __restrict__ Qw, const float* __restrict__ Kw,
                           const float* __restrict__ Vw, const float* __restrict__ Ww,
                           const float* __restrict__ Ew, US* __restrict__ arena){
  int i = blockIdx.x * 256 + threadIdx.x;
  int g = i >> 8, n = i & 255;
  const float* src; int row0;
  if      (g <  32){ src = Qw; row0 = g*8; }
  else if (g <  64){ src = Kw; row0 = (g-32)*8; }
  else if (g <  96){ src = Kw; row0 = 256 + (g-64)*8; }
  else if (g < 128){ src = Vw; row0 = (g-96)*8; }
  else if (g < 160){ src = Vw; row0 = 256 + (g-128)*8; }
  else if (g < 224){ src = Ww; row0 = (g-160)*8; }
  else if (g < 256){ src = Ew; row0 = (g-224)*8; }
  else if (g < 288){ src = Ew; row0 = 256 + (g-256)*8; }
  else             { src = Ew; row0 = 512 + (g-288)*8; }
  union { US h[8]; uint4 q; } pk;
#pragma unroll
  for (int j = 0; j < 8; ++j) pk.h[j] = f2bf(src[(size_t)(row0 + j)*DD + n]);
  *(uint4*)(arena + (size_t)g*2048 + n*8) = pk.q;
}

// ---- multi-output node GEMM: C_y = A[M][256] @ B_y + bias_y ; y = blockIdx.y
template<typename AT, typename OT>
__global__ __launch_bounds__(256, 2)
void gemm_nmulti_k(const AT* __restrict__ p0,
                   const US* bp0, const float* b0, OT* o0,
                   const US* bp1, const float* b1, OT* o1,
                   const US* bp2, const float* b2, OT* o2, int M)
{
  const US* Bp  = (blockIdx.y == 0) ? bp0 : (blockIdx.y == 1 ? bp1 : bp2);
  const float* bias = (blockIdx.y == 0) ? b0 : (blockIdx.y == 1 ? b1 : b2);
  OT* out = (blockIdx.y == 0) ? o0 : (blockIdx.y == 1 ? o1 : o2);
  __shared__ __align__(16) US Alds[64][40];
  __shared__ __align__(16) US Blds[8192];
  const int tid  = threadIdx.x;
  const int lane = tid & 63;
  const int wav  = tid >> 6;
  const int bm   = blockIdx.x * 64;

  floatx4 acc[4][4];
#pragma unroll
  for (int i = 0; i < 4; ++i)
#pragma unroll
    for (int j = 0; j < 4; ++j) acc[i][j] = (floatx4){0.f,0.f,0.f,0.f};

  const int ar = tid >> 2;
  const int ak = (tid & 3) << 3;
  int grow = bm + ar; if (grow > M - 1) grow = M - 1;
  const AT* rA = p0 + (size_t)grow * DD;
  const int rq = lane >> 4;
  const int cl = lane & 15;

  uint4 arow[8];
#pragma unroll
  for (int t = 0; t < 8; ++t) {
    float av[8]; ld8(rA + t*32 + ak, av);
    arow[t] = pack8(av);
  }

  for (int t = 0; t < 8; ++t) {
    *(uint4*)&Alds[ar][ak] = arow[t];
    const uint4* bsrc = (const uint4*)(Bp + (size_t)(t*4) * 2048);
    uint4* bdst = (uint4*)Blds;
#pragma unroll
    for (int u = 0; u < 4; ++u) bdst[tid + u*256] = bsrc[tid + u*256];
    __syncthreads();

    short8v af[4], bfr[4];
#pragma unroll
    for (int i = 0; i < 4; ++i) af[i] = *(const short8v*)&Alds[i*16 + cl][rq*8];
#pragma unroll
    for (int j = 0; j < 4; ++j) bfr[j] = *(const short8v*)&Blds[(size_t)(rq*256 + wav*64 + j*16 + cl) * 8];
#pragma unroll
    for (int i = 0; i < 4; ++i)
#pragma unroll
      for (int j = 0; j < 4; ++j)
        acc[i][j] = __builtin_amdgcn_mfma_f32_16x16x32_bf16(af[i], bfr[j], acc[i][j], 0, 0, 0);
    __syncthreads();
  }

#pragma unroll
  for (int i = 0; i < 4; ++i)
#pragma unroll
    for (int r = 0; r < 4; ++r) {
      int gm = bm + i*16 + rq*4 + r;
      if (gm < M) {
#pragma unroll
        for (int j = 0; j < 4; ++j) {
          int n = wav*64 + j*16 + cl;
          float b = bias ? bias[n] : 0.f;
          st1(out + (size_t)gm*DD + n, acc[i][j][r] + b);
        }
      }
    }
}

// ---- W GEMM: A=[agg(f32), hn(AT)] K=512 -> raw f32 + LN(OT)
template<typename AT, typename OT>
__global__ __launch_bounds__(256, 2)
void gemm_w_k(const float* __restrict__ p0, const AT* __restrict__ p1,
              const US* __restrict__ Bp, const float* __restrict__ bias,
              const float* __restrict__ lg, const float* __restrict__ lb,
              float* __restrict__ Craw, OT* __restrict__ Cln, int M)
{
  __shared__ __align__(16) US Alds[64][40];
  __shared__ __align__(16) US Blds[8192];
  __shared__ float S1[4][64], S2[4][64];
  const int tid  = threadIdx.x;
  const int lane = tid & 63;
  const int wav  = tid >> 6;
  const int bm   = blockIdx.x * 64;

  floatx4 acc[4][4];
#pragma unroll
  for (int i = 0; i < 4; ++i)
#pragma unroll
    for (int j = 0; j < 4; ++j) acc[i][j] = (floatx4){0.f,0.f,0.f,0.f};

  const int ar = tid >> 2;
  const int ak = (tid & 3) << 3;
  int grow = bm + ar; if (grow > M - 1) grow = M - 1;
  const float* rA = p0 + (size_t)grow * DD;
  const AT*    rB = p1 + (size_t)grow * DD;
  const int rq = lane >> 4;
  const int cl = lane & 15;

  uint4 arow[16];
#pragma unroll
  for (int t = 0; t < 16; ++t) {
    const int kk = t*32 + ak;
    float av[8];
    if (kk < DD) ld8(rA + kk, av); else ld8(rB + kk - DD, av);
    arow[t] = pack8(av);
  }

  for (int t = 0; t < 16; ++t) {
    *(uint4*)&Alds[ar][ak] = arow[t];
    const uint4* bsrc = (const uint4*)(Bp + (size_t)(t*4) * 2048);
    uint4* bdst = (uint4*)Blds;
#pragma unroll
    for (int u = 0; u < 4; ++u) bdst[tid + u*256] = bsrc[tid + u*256];
    __syncthreads();

    short8v af[4], bfr[4];
#pragma unroll
    for (int i = 0; i < 4; ++i) af[i] = *(const short8v*)&Alds[i*16 + cl][rq*8];
#pragma unroll
    for (int j = 0; j < 4; ++j) bfr[j] = *(const short8v*)&Blds[(size_t)(rq*256 + wav*64 + j*16 + cl) * 8];
#pragma unroll
    for (int i = 0; i < 4; ++i)
#pragma unroll
      for (int j = 0; j < 4; ++j)
        acc[i][j] = __builtin_amdgcn_mfma_f32_16x16x32_bf16(af[i], bfr[j], acc[i][j], 0, 0, 0);
    __syncthreads();
  }

#pragma unroll
  for (int i = 0; i < 4; ++i)
#pragma unroll
    for (int j = 0; j < 4; ++j) {
      int n = wav*64 + j*16 + cl;
      float bs = bias[n];
#pragma unroll
      for (int r = 0; r < 4; ++r) {
        int gm = bm + i*16 + rq*4 + r;
        float val = acc[i][j][r] + bs;
        if (gm < M) Craw[(size_t)gm*DD + n] = val;
        acc[i][j][r] = fmaxf(val, 0.f);
      }
    }
#pragma unroll
  for (int i = 0; i < 4; ++i)
#pragma unroll
    for (int r = 0; r < 4; ++r) {
      float s1 = 0.f, s2 = 0.f;
#pragma unroll
      for (int j = 0; j < 4; ++j){ float v = acc[i][j][r]; s1 += v; s2 += v*v; }
#pragma unroll
      for (int o = 1; o < 16; o <<= 1){ s1 += __shfl_xor(s1, o, 64); s2 += __shfl_xor(s2, o, 64); }
      if (cl == 0){ S1[wav][i*16 + rq*4 + r] = s1; S2[wav][i*16 + rq*4 + r] = s2; }
    }
  __syncthreads();
#pragma unroll
  for (int i = 0; i < 4; ++i)
#pragma unroll
    for (int r = 0; r < 4; ++r) {
      int rr = i*16 + rq*4 + r;
      float t1 = S1[0][rr] + S1[1][rr] + S1[2][rr] + S1[3][rr];
      float t2 = S2[0][rr] + S2[1][rr] + S2[2][rr] + S2[3][rr];
      float mu = t1 * (1.f/256.f);
      float var = t2 * (1.f/256.f) - mu*mu;
      float rs = rsqrtf(fmaxf(var, 0.f) + LEPS);
      int gm = bm + i*16 + rq*4 + r;
      if (gm < M) {
#pragma unroll
        for (int j = 0; j < 4; ++j) {
          int n = wav*64 + j*16 + cl;
          st1(Cln + (size_t)gm*DD + n, (acc[i][j][r] - mu) * rs * lg[n] + lb[n]);
        }
      }
    }
}

// ---- edge K+V GEMM, src-sorted edge order: row i handles edge e=esrc[i].
// A = hn[src[e]]∘he[e] (K=256), dual B, += KN/VN[src[e]], out to CSR slot eperm[e].
template<typename AT>
__global__ __launch_bounds__(256, 2)
void gemm_kve_k(const AT* __restrict__ p0, const AT* __restrict__ p1,
                const int* __restrict__ srcI, const int* __restrict__ esrc,
                const US* __restrict__ BpK, const US* __restrict__ BpV,
                const US* __restrict__ KN, const US* __restrict__ VN,
                const int* __restrict__ eperm,
                US* __restrict__ Km, US* __restrict__ Vm, int M)
{
  __shared__ __align__(16) US Alds[64][40];
  __shared__ __align__(16) US BldsK[8192];
  __shared__ __align__(16) US BldsV[8192];
  const int tid  = threadIdx.x;
  const int lane = tid & 63;
  const int wav  = tid >> 6;
  const int bm   = blockIdx.x * 64;

  floatx4 accK[4][4], accV[4][4];
#pragma unroll
  for (int i = 0; i < 4; ++i)
#pragma unroll
    for (int j = 0; j < 4; ++j){ accK[i][j] = (floatx4){0.f,0.f,0.f,0.f}; accV[i][j] = (floatx4){0.f,0.f,0.f,0.f}; }

  const int ar = tid >> 2;
  const int ak = (tid & 3) << 3;
  int grow = bm + ar; if (grow > M - 1) grow = M - 1;
  int e = esrc[grow];
  int s = srcI[e];
  const AT* rA = p0 + (size_t)s * DD;
  const AT* rB = p1 + (size_t)e * DD;
  const int rq = lane >> 4;
  const int cl = lane & 15;

  for (int t = 0; t < 8; ++t) {
    const int kk = t*32 + ak;
    float av[8], bv[8];
    ld8(rA + kk, av); ld8(rB + kk, bv);
    float mv[8];
#pragma unroll
    for (int j = 0; j < 8; ++j) mv[j] = av[j] * bv[j];
    *(uint4*)&Alds[ar][ak] = pack8(mv);

    const uint4* bsK = (const uint4*)(BpK + (size_t)(t*4) * 2048);
    const uint4* bsV = (const uint4*)(BpV + (size_t)(t*4) * 2048);
    uint4* bdK = (uint4*)BldsK; uint4* bdV = (uint4*)BldsV;
#pragma unroll
    for (int u = 0; u < 4; ++u){ bdK[tid + u*256] = bsK[tid + u*256]; bdV[tid + u*256] = bsV[tid + u*256]; }
    __syncthreads();

    short8v af[4], bK4[4], bV4[4];
#pragma unroll
    for (int i = 0; i < 4; ++i) af[i] = *(const short8v*)&Alds[i*16 + cl][rq*8];
#pragma unroll
    for (int j = 0; j < 4; ++j){
      size_t bi = (size_t)(rq*256 + wav*64 + j*16 + cl) * 8;
      bK4[j] = *(const short8v*)&BldsK[bi];
      bV4[j] = *(const short8v*)&BldsV[bi];
    }
#pragma unroll
    for (int i = 0; i < 4; ++i)
#pragma unroll
      for (int j = 0; j < 4; ++j){
        accK[i][j] = __builtin_amdgcn_mfma_f32_16x16x32_bf16(af[i], bK4[j], accK[i][j], 0, 0, 0);
        accV[i][j] = __builtin_amdgcn_mfma_f32_16x16x32_bf16(af[i], bV4[j], accV[i][j], 0, 0, 0);
      }
    __syncthreads();
  }

#pragma unroll
  for (int i = 0; i < 4; ++i)
#pragma unroll
    for (int r = 0; r < 4; ++r) {
      int gm = bm + i*16 + rq*4 + r;
      if (gm < M) {
        int eg = esrc[gm];
        int pg = eperm[eg];
        int sg = srcI[eg];
        const US* kn = KN + (size_t)sg * DD;
        const US* vn = VN + (size_t)sg * DD;
#pragma unroll
        for (int j = 0; j < 4; ++j) {
          int n = wav*64 + j*16 + cl;
          Km[(size_t)pg*DD + n] = f2bf(accK[i][j][r] + bf2f(kn[n]));
          Vm[(size_t)pg*DD + n] = f2bf(accV[i][j][r] + bf2f(vn[n]));
        }
      }
    }
}

// ---- edge E GEMM: A = h_e (K=256 stream), += EN1[src]+EN2[dst] (bf16), relu+LN -> OT
template<typename AT, typename OT>
__global__ __launch_bounds__(256, 2)
void gemm_e_k(const AT* __restrict__ he, const int* __restrict__ srcI,
              const int* __restrict__ dstI, const US* __restrict__ Bp,
              const US* __restrict__ EN1, const US* __restrict__ EN2,
              const float* __restrict__ lg, const float* __restrict__ lb,
              OT* __restrict__ Cln, int M)
{
  __shared__ __align__(16) US Alds[64][40];
  __shared__ __align__(16) US Blds[8192];
  __shared__ float S1[4][64], S2[4][64];
  const int tid  = threadIdx.x;
  const int lane = tid & 63;
  const int wav  = tid >> 6;
  const int bm   = blockIdx.x * 64;

  floatx4 acc[4][4];
#pragma unroll
  for (int i = 0; i < 4; ++i)
#pragma unroll
    for (int j = 0; j < 4; ++j) acc[i][j] = (floatx4){0.f,0.f,0.f,0.f};

  const int ar = tid >> 2;
  const int ak = (tid & 3) << 3;
  int grow = bm + ar; if (grow > M - 1) grow = M - 1;
  const AT* rA = he + (size_t)grow * DD;
  const int rq = lane >> 4;
  const int cl = lane & 15;

  uint4 arow[8];
#pragma unroll
  for (int t = 0; t < 8; ++t) {
    float av[8]; ld8(rA + t*32 + ak, av);
    arow[t] = pack8(av);
  }

  for (int t = 0; t < 8; ++t) {
    *(uint4*)&Alds[ar][ak] = arow[t];
    const uint4* bsrc = (const uint4*)(Bp + (size_t)(t*4) * 2048);
    uint4* bdst = (uint4*)Blds;
#pragma unroll
    for (int u = 0; u < 4; ++u) bdst[tid + u*256] = bsrc[tid + u*256];
    __syncthreads();

    short8v af[4], bfr[4];
#pragma unroll
    for (int i = 0; i < 4; ++i) af[i] = *(const short8v*)&Alds[i*16 + cl][rq*8];
#pragma unroll
    for (int j = 0; j < 4; ++j) bfr[j] = *(const short8v*)&Blds[(size_t)(rq*256 + wav*64 + j*16 + cl) * 8];
#pragma unroll
    for (int i = 0; i < 4; ++i)
#pragma unroll
      for (int j = 0; j < 4; ++j)
        acc[i][j] = __builtin_amdgcn_mfma_f32_16x16x32_bf16(af[i], bfr[j], acc[i][j], 0, 0, 0);
    __syncthreads();
  }

#pragma unroll
  for (int i = 0; i < 4; ++i)
#pragma unroll
    for (int r = 0; r < 4; ++r) {
      int gm = bm + i*16 + rq*4 + r;
      int gmc = (gm < M) ? gm : (M - 1);
      const US* e1 = EN1 + (size_t)srcI[gmc] * DD;
      const US* e2 = EN2 + (size_t)dstI[gmc] * DD;
#pragma unroll
      for (int j = 0; j < 4; ++j) {
        int n = wav*64 + j*16 + cl;
        float val = acc[i][j][r] + bf2f(e1[n]) + bf2f(e2[n]);
        acc[i][j][r] = fmaxf(val, 0.f);
      }
    }
#pragma unroll
  for (int i = 0; i < 4; ++i)
#pragma unroll
    for (int r = 0; r < 4; ++r) {
      float s1 = 0.f, s2 = 0.f;
#pragma unroll
      for (int j = 0; j < 4; ++j){ float v = acc[i][j][r]; s1 += v; s2 += v*v; }
#pragma unroll
      for (int o = 1; o < 16; o <<= 1){ s1 += __shfl_xor(s1, o, 64); s2 += __shfl_xor(s2, o, 64); }
      if (cl == 0){ S1[wav][i*16 + rq*4 + r] = s1; S2[wav][i*16 + rq*4 + r] = s2; }
    }
  __syncthreads();
#pragma unroll
  for (int i = 0; i < 4; ++i)
#pragma unroll
    for (int r = 0; r < 4; ++r) {
      int rr = i*16 + rq*4 + r;
      float t1 = S1[0][rr] + S1[1][rr] + S1[2][rr] + S1[3][rr];
      float t2 = S2[0][rr] + S2[1][rr] + S2[2][rr] + S2[3][rr];
      float mu = t1 * (1.f/256.f);
      float var = t2 * (1.f/256.f) - mu*mu;
      float rs = rsqrtf(fmaxf(var, 0.f) + LEPS);
      int gm = bm + i*16 + rq*4 + r;
      if (gm < M) {
#pragma unroll
        for (int j = 0; j < 4; ++j) {
          int n = wav*64 + j*16 + cl;
          st1(Cln + (size_t)gm*DD + n, (acc[i][j][r] - mu) * rs * lg[n] + lb[n]);
        }
      }
    }
}

// ---- CSR builds
__global__ void count_k(const int* __restrict__ key, int* __restrict__ cnt, int e){
  int i = blockIdx.x * blockDim.x + threadIdx.x;
  if (i < e) atomicAdd(&cnt[key[i]], 1);
}
__global__ void scan_k(const int* __restrict__ cnt, int* __restrict__ rp, int n){
  __shared__ int part[256];
  const int t = threadIdx.x;
  const int chunk = (n + 255) / 256;
  int lo = t * chunk, hi = lo + chunk; if (hi > n) hi = n; if (lo > n) lo = n;
  int s = 0;
  for (int i = lo; i < hi; ++i) s += cnt[i];
  part[t] = s; __syncthreads();
  if (t == 0){ int run = 0; for (int i = 0; i < 256; ++i){ int tmp = part[i]; part[i] = run; run += tmp; } rp[n] = run; }
  __syncthreads();
  int run = part[t];
  for (int i = lo; i < hi; ++i){ rp[i] = run; run += cnt[i]; }
}
__global__ void scatter_k(const int* __restrict__ key, const int* __restrict__ rp,
                          int* __restrict__ pos, int* __restrict__ eperm, int e){
  int i = blockIdx.x * blockDim.x + threadIdx.x;
  if (i >= e) return;
  int d = key[i];
  int p = atomicAdd(&pos[d], 1);
  eperm[i] = rp[d] + p;
}
__global__ void scatter_col_k(const int* __restrict__ key, const int* __restrict__ rp,
                              int* __restrict__ pos, int* __restrict__ col, int e){
  int i = blockIdx.x * blockDim.x + threadIdx.x;
  if (i >= e) return;
  int d = key[i];
  int p = atomicAdd(&pos[d], 1);
  col[rp[d] + p] = i;
}

// ---- per-node online softmax + aggregation; K/V in CSR order -> sequential reads
__global__ __launch_bounds__(256)
void node_agg_k(const int* __restrict__ rp,
                const US* __restrict__ Q, const US* __restrict__ Km,
                const US* __restrict__ Vm, float* __restrict__ agg)
{
  int d = blockIdx.x, f = threadIdx.x;
  int beg = rp[d], end = rp[d + 1];
  float q = bf2f(Q[(size_t)d * DD + f]);
  float m = -3.0e38f, z = 0.f, s = 0.f;
  for (int i = beg; i < end; ++i){
    float a  = q * bf2f(Km[(size_t)i * DD + f]);
    float vv = bf2f(Vm[(size_t)i * DD + f]);
    float mn = fmaxf(m, a);
    float sc = __expf(m - mn);
    float w  = __expf(a - mn);
    z = z * sc + w;
    s = s * sc + w * vv;
    m = mn;
  }
  agg[(size_t)d * DD + f] = (z > 0.f) ? (s / z) : 0.f;
}

__global__ void sentinel_k(int hostbits, float* out){
  int code = 0;
  if (hostbits & 1) code = 1;
  else if (hostbits & 2) code = 2;
  else if (hostbits & 4) code = 3;
  else if (hostbits & 8) code = 4;
  if (code) out[0] = (float)code * 1.0e6f;
}

// ---------------- per-layer driver ----------------
struct Bufs {
  float *agg, *hn_new;
  US *QN, *KN, *VN, *EN1, *EN2, *Kmat, *Vmat, *arena;
  int *rp, *eperm, *esrc;
  const int *src, *dst;
  const float *lg, *lb;
};
template<typename AT, typename OT>
static void layer_run(const Bufs& B, const AT* hn_in, const AT* he_in,
                      OT* hn_out, OT* he_out,
                      const float* Kb, const float* Vb, const float* Qb,
                      const float* Wb, const float* Eb, hipStream_t stream)
{
  const int gN = (NN + 63) / 64, gE = (NE + 63) / 64;
  gemm_nmulti_k<AT, US><<<dim3(gN, 3), 256, 0, stream>>>(hn_in,
      B.arena + AOFF_Q, Qb, B.QN,
      B.arena + AOFF_K2, Kb, B.KN,
      B.arena + AOFF_V2, Vb, B.VN, NN);
  gemm_kve_k<AT><<<gE, 256, 0, stream>>>(hn_in, he_in, B.src, B.esrc,
      B.arena + AOFF_K1, B.arena + AOFF_V1, B.KN, B.VN, B.eperm, B.Kmat, B.Vmat, NE);
  node_agg_k<<<NN, 256, 0, stream>>>(B.rp, B.QN, B.Kmat, B.Vmat, B.agg);
  gemm_w_k<AT, OT><<<gN, 256, 0, stream>>>(B.agg, hn_in, B.arena + AOFF_W, Wb,
      B.lg, B.lb, B.hn_new, hn_out, NN);
  gemm_nmulti_k<float, US><<<dim3(gN, 2), 256, 0, stream>>>(B.hn_new,
      B.arena + AOFF_E1, Eb, B.EN1,  B.arena + AOFF_E2, nullptr, B.EN2,
      B.arena + AOFF_E2, nullptr, B.EN2, NN);
  gemm_e_k<AT, OT><<<gE, 256, 0, stream>>>(he_in, B.src, B.dst, B.arena + AOFF_E3,
      B.EN1, B.EN2, B.lg, B.lb, he_out, NE);
}

extern "C" void kernel_launch(void* const* d_in, const int* in_sizes, int n_in,
                              void* d_out, int out_size, void* d_ws, size_t ws_size,
                              hipStream_t stream) {
  const float* node_h = (const float*)d_in[0];
  const float* edge_h = (const float*)d_in[1];
  const int*   src    = (const int*)d_in[2];
  const int*   dst    = (const int*)d_in[3];
  const float* Kw = (const float*)d_in[4];  const float* Kb = (const float*)d_in[5];
  const float* Vw = (const float*)d_in[6];  const float* Vb = (const float*)d_in[7];
  const float* Qw = (const float*)d_in[8];  const float* Qb = (const float*)d_in[9];
  const float* Ww = (const float*)d_in[10]; const float* Wb = (const float*)d_in[11];
  const float* Ew = (const float*)d_in[12]; const float* Eb = (const float*)d_in[13];
  const float* ln_g = (const float*)d_in[14];
  const float* ln_b = (const float*)d_in[15];

  char* w = (char*)d_ws; size_t off = 0;
  auto alloc = [&](size_t bytes)->char* {
    char* p = w + off; off += (bytes + 255) & ~(size_t)255; return p;
  };
  float* agg    = (float*)alloc((size_t)NN * DD * 4);
  float* hn_new = (float*)alloc((size_t)NN * DD * 4);
  US* QN     = (US*)alloc((size_t)NN * DD * 2);
  US* hn_cur = (US*)alloc((size_t)NN * DD * 2);
  US* KN     = (US*)alloc((size_t)NN * DD * 2);
  US* VN     = (US*)alloc((size_t)NN * DD * 2);
  US* EN1    = (US*)alloc((size_t)NN * DD * 2);
  US* EN2    = (US*)alloc((size_t)NN * DD * 2);
  US* Kmat   = (US*)alloc((size_t)NE * DD * 2);
  US* Vmat   = (US*)alloc((size_t)NE * DD * 2);
  US* he_cur = (US*)alloc((size_t)NE * DD * 2);
  US* arena  = (US*)alloc((size_t)320 * 2048 * 2);
  int* cnt   = (int*)alloc((size_t)NN * 4);
  int* rp    = (int*)alloc((size_t)(NN + 1) * 4);
  int* rpS   = (int*)alloc((size_t)(NN + 1) * 4);
  int* pos   = (int*)alloc((size_t)NN * 4);
  int* eperm = (int*)alloc((size_t)NE * 4);
  int* esrc  = (int*)alloc((size_t)NE * 4);

  float* out_hn = (float*)d_out;
  float* out_he = out_hn + (size_t)NN * DD;

  int hostbits = 0;
  {
    static const int exp_sizes[16] = {NN*DD, NE*DD, NE, NE, 2*512*DD, 2*DD, 2*512*DD, 2*DD,
                                      2*DD*DD, 2*DD, 2*512*DD, 2*DD, 2*768*DD, 2*DD, DD, DD};
    if (n_in != 16) hostbits |= 2;
    else { for (int i = 0; i < 16; ++i) if (in_sizes[i] != exp_sizes[i]) hostbits |= 2; }
    if (out_size != NN*DD + NE*DD) hostbits |= 4;
    if (off > ws_size) hostbits |= 1;
  }
  if (hostbits) {
    sentinel_k<<<1, 1, 0, stream>>>(hostbits, out_hn);
    return;
  }

  // CSR over dst -> eperm (edge -> CSR slot); CSR over src -> esrc (src-sorted edge list)
  hipMemsetAsync(cnt, 0, (size_t)NN * 4, stream);
  hipMemsetAsync(pos, 0, (size_t)NN * 4, stream);
  count_k<<<(NE + 255)/256, 256, 0, stream>>>(dst, cnt, NE);
  scan_k<<<1, 256, 0, stream>>>(cnt, rp, NN);
  scatter_k<<<(NE + 255)/256, 256, 0, stream>>>(dst, rp, pos, eperm, NE);
  hipMemsetAsync(cnt, 0, (size_t)NN * 4, stream);
  hipMemsetAsync(pos, 0, (size_t)NN * 4, stream);
  count_k<<<(NE + 255)/256, 256, 0, stream>>>(src, cnt, NE);
  scan_k<<<1, 256, 0, stream>>>(cnt, rpS, NN);
  scatter_col_k<<<(NE + 255)/256, 256, 0, stream>>>(src, rpS, pos, esrc, NE);

  Bufs B{agg, hn_new, QN, KN, VN, EN1, EN2, Kmat, Vmat, arena, rp, eperm, esrc,
         src, dst, ln_g, ln_b};

  // layer 0: f32 inputs -> bf16 hn_cur/he_cur
  pack_all_k<<<320, 256, 0, stream>>>(Qw, Kw, Vw, Ww, Ew, arena);
  layer_run<float, US>(B, node_h, edge_h, hn_cur, he_cur,
                       Kb, Vb, Qb, Wb, Eb, stream);
  // layer 1: bf16 inputs -> f32 d_out
  pack_all_k<<<320, 256, 0, stream>>>(Qw + (size_t)256*DD, Kw + (size_t)512*DD,
                                      Vw + (size_t)512*DD, Ww + (size_t)512*DD,
                                      Ew + (size_t)768*DD, arena);
  layer_run<US, float>(B, hn_cur, he_cur, out_hn, out_he,
                       Kb + DD, Vb + DD, Qb + DD, Wb + DD, Eb + DD, stream);

  if (hipGetLastError() != hipSuccess) {
    sentinel_k<<<1, 1, 0, stream>>>(8, out_hn);
  }
}

// Round 18
// 786.254 us; speedup vs baseline: 1.1835x; 1.1835x over previous
//
#include <hip/hip_runtime.h>

#define NN 10000
#define NE 160000
#define DD 256
#define LEPS 1e-5f

typedef __attribute__((ext_vector_type(8))) short short8v;
typedef __attribute__((ext_vector_type(4))) float floatx4;
typedef unsigned short US;

static __device__ __forceinline__ US f2bf(float f){
  unsigned u = __builtin_bit_cast(unsigned, f);
  u += 0x7FFFu + ((u >> 16) & 1u);
  return (US)(u >> 16);
}
static __device__ __forceinline__ float bf2f(US s){
  unsigned u = ((unsigned)s) << 16;
  return __builtin_bit_cast(float, u);
}
template<typename T>
static __device__ __forceinline__ void ld8(const T* p, float* o){
  if constexpr (sizeof(T) == 2) {
    union { US h[8]; uint4 q; } u;
    u.q = *(const uint4*)p;
#pragma unroll
    for (int j = 0; j < 8; ++j) o[j] = bf2f(u.h[j]);
  } else {
    float4 a = *(const float4*)p; float4 b = *(const float4*)(p + 4);
    o[0]=a.x; o[1]=a.y; o[2]=a.z; o[3]=a.w; o[4]=b.x; o[5]=b.y; o[6]=b.z; o[7]=b.w;
  }
}
template<typename OT>
static __device__ __forceinline__ void st1(OT* p, float v){
  if constexpr (sizeof(OT) == 2) *p = (OT)f2bf(v); else *p = (OT)v;
}
static __device__ __forceinline__ uint4 pack8(const float* a){
  union { US h[8]; uint4 q; } pk;
#pragma unroll
  for (int j = 0; j < 8; ++j) pk.h[j] = f2bf(a[j]);
  return pk.q;
}

// ---- pack ALL layer weights into fragment-ready arena (kb-blocks of 2048 US)
#define AOFF_Q  0
#define AOFF_K1 (32*2048)
#define AOFF_K2 (64*2048)
#define AOFF_V1 (96*2048)
#define AOFF_V2 (128*2048)
#define AOFF_W  (160*2048)
#define AOFF_E1 (224*2048)
#define AOFF_E2 (256*2048)
#define AOFF_E3 (288*2048)
__global__ void pack_all_k(const float* __restrict__ Qw, const float* __restrict__ Kw,
                           const float* __restrict__ Vw, const float* __restrict__ Ww,
                           const float* __restrict__ Ew, US* __restrict__ arena){
  int i = blockIdx.x * 256 + threadIdx.x;
  int g = i >> 8, n = i & 255;
  const float* src; int row0;
  if      (g <  32){ src = Qw; row0 = g*8; }
  else if (g <  64){ src = Kw; row0 = (g-32)*8; }
  else if (g <  96){ src = Kw; row0 = 256 + (g-64)*8; }
  else if (g < 128){ src = Vw; row0 = (g-96)*8; }
  else if (g < 160){ src = Vw; row0 = 256 + (g-128)*8; }
  else if (g < 224){ src = Ww; row0 = (g-160)*8; }
  else if (g < 256){ src = Ew; row0 = (g-224)*8; }
  else if (g < 288){ src = Ew; row0 = 256 + (g-256)*8; }
  else             { src = Ew; row0 = 512 + (g-288)*8; }
  union { US h[8]; uint4 q; } pk;
#pragma unroll
  for (int j = 0; j < 8; ++j) pk.h[j] = f2bf(src[(size_t)(row0 + j)*DD + n]);
  *(uint4*)(arena + (size_t)g*2048 + n*8) = pk.q;
}

// ---- multi-output node GEMM: C_y = A[M][256] @ B_y + bias_y ; y = blockIdx.y
template<typename AT, typename OT>
__global__ __launch_bounds__(256, 2)
void gemm_nmulti_k(const AT* __restrict__ p0,
                   const US* bp0, const float* b0, OT* o0,
                   const US* bp1, const float* b1, OT* o1,
                   const US* bp2, const float* b2, OT* o2, int M)
{
  const US* Bp  = (blockIdx.y == 0) ? bp0 : (blockIdx.y == 1 ? bp1 : bp2);
  const float* bias = (blockIdx.y == 0) ? b0 : (blockIdx.y == 1 ? b1 : b2);
  OT* out = (blockIdx.y == 0) ? o0 : (blockIdx.y == 1 ? o1 : o2);
  __shared__ __align__(16) US Alds[64][40];
  __shared__ __align__(16) US Blds[8192];
  const int tid  = threadIdx.x;
  const int lane = tid & 63;
  const int wav  = tid >> 6;
  const int bm   = blockIdx.x * 64;

  floatx4 acc[4][4];
#pragma unroll
  for (int i = 0; i < 4; ++i)
#pragma unroll
    for (int j = 0; j < 4; ++j) acc[i][j] = (floatx4){0.f,0.f,0.f,0.f};

  const int ar = tid >> 2;
  const int ak = (tid & 3) << 3;
  int grow = bm + ar; if (grow > M - 1) grow = M - 1;
  const AT* rA = p0 + (size_t)grow * DD;
  const int rq = lane >> 4;
  const int cl = lane & 15;

  for (int k0 = 0; k0 < 256; k0 += 32) {
    float av[8]; ld8(rA + k0 + ak, av);
    union { US h[8]; uint4 q; } pk;
#pragma unroll
    for (int j = 0; j < 8; ++j) pk.h[j] = f2bf(av[j]);
    *(uint4*)&Alds[ar][ak] = pk.q;

    const uint4* bsrc = (const uint4*)(Bp + (size_t)(k0 >> 3) * 2048);
    uint4* bdst = (uint4*)Blds;
#pragma unroll
    for (int u = 0; u < 4; ++u) bdst[tid + u*256] = bsrc[tid + u*256];
    __syncthreads();

    short8v af[4], bfr[4];
#pragma unroll
    for (int i = 0; i < 4; ++i) af[i] = *(const short8v*)&Alds[i*16 + cl][rq*8];
#pragma unroll
    for (int j = 0; j < 4; ++j) bfr[j] = *(const short8v*)&Blds[(size_t)(rq*256 + wav*64 + j*16 + cl) * 8];
#pragma unroll
    for (int i = 0; i < 4; ++i)
#pragma unroll
      for (int j = 0; j < 4; ++j)
        acc[i][j] = __builtin_amdgcn_mfma_f32_16x16x32_bf16(af[i], bfr[j], acc[i][j], 0, 0, 0);
    __syncthreads();
  }

#pragma unroll
  for (int i = 0; i < 4; ++i)
#pragma unroll
    for (int r = 0; r < 4; ++r) {
      int gm = bm + i*16 + rq*4 + r;
      if (gm < M) {
#pragma unroll
        for (int j = 0; j < 4; ++j) {
          int n = wav*64 + j*16 + cl;
          float b = bias ? bias[n] : 0.f;
          st1(out + (size_t)gm*DD + n, acc[i][j][r] + b);
        }
      }
    }
}

// ---- W GEMM: A=[agg(f32), hn(AT)] K=512 -> raw f32 + LN(OT)
template<typename AT, typename OT>
__global__ __launch_bounds__(256, 2)
void gemm_w_k(const float* __restrict__ p0, const AT* __restrict__ p1,
              const US* __restrict__ Bp, const float* __restrict__ bias,
              const float* __restrict__ lg, const float* __restrict__ lb,
              float* __restrict__ Craw, OT* __restrict__ Cln, int M)
{
  __shared__ __align__(16) US Alds[64][40];
  __shared__ __align__(16) US Blds[8192];
  __shared__ float S1[4][64], S2[4][64];
  const int tid  = threadIdx.x;
  const int lane = tid & 63;
  const int wav  = tid >> 6;
  const int bm   = blockIdx.x * 64;

  floatx4 acc[4][4];
#pragma unroll
  for (int i = 0; i < 4; ++i)
#pragma unroll
    for (int j = 0; j < 4; ++j) acc[i][j] = (floatx4){0.f,0.f,0.f,0.f};

  const int ar = tid >> 2;
  const int ak = (tid & 3) << 3;
  int grow = bm + ar; if (grow > M - 1) grow = M - 1;
  const float* rA = p0 + (size_t)grow * DD;
  const AT*    rB = p1 + (size_t)grow * DD;
  const int rq = lane >> 4;
  const int cl = lane & 15;

  for (int k0 = 0; k0 < 512; k0 += 32) {
    const int kk = k0 + ak;
    float av[8];
    if (kk < DD) ld8(rA + kk, av); else ld8(rB + kk - DD, av);
    union { US h[8]; uint4 q; } pk;
#pragma unroll
    for (int j = 0; j < 8; ++j) pk.h[j] = f2bf(av[j]);
    *(uint4*)&Alds[ar][ak] = pk.q;

    const uint4* bsrc = (const uint4*)(Bp + (size_t)(k0 >> 3) * 2048);
    uint4* bdst = (uint4*)Blds;
#pragma unroll
    for (int u = 0; u < 4; ++u) bdst[tid + u*256] = bsrc[tid + u*256];
    __syncthreads();

    short8v af[4], bfr[4];
#pragma unroll
    for (int i = 0; i < 4; ++i) af[i] = *(const short8v*)&Alds[i*16 + cl][rq*8];
#pragma unroll
    for (int j = 0; j < 4; ++j) bfr[j] = *(const short8v*)&Blds[(size_t)(rq*256 + wav*64 + j*16 + cl) * 8];
#pragma unroll
    for (int i = 0; i < 4; ++i)
#pragma unroll
      for (int j = 0; j < 4; ++j)
        acc[i][j] = __builtin_amdgcn_mfma_f32_16x16x32_bf16(af[i], bfr[j], acc[i][j], 0, 0, 0);
    __syncthreads();
  }

#pragma unroll
  for (int i = 0; i < 4; ++i)
#pragma unroll
    for (int j = 0; j < 4; ++j) {
      int n = wav*64 + j*16 + cl;
      float bs = bias[n];
#pragma unroll
      for (int r = 0; r < 4; ++r) {
        int gm = bm + i*16 + rq*4 + r;
        float val = acc[i][j][r] + bs;
        if (gm < M) Craw[(size_t)gm*DD + n] = val;
        acc[i][j][r] = fmaxf(val, 0.f);
      }
    }
#pragma unroll
  for (int i = 0; i < 4; ++i)
#pragma unroll
    for (int r = 0; r < 4; ++r) {
      float s1 = 0.f, s2 = 0.f;
#pragma unroll
      for (int j = 0; j < 4; ++j){ float v = acc[i][j][r]; s1 += v; s2 += v*v; }
#pragma unroll
      for (int o = 1; o < 16; o <<= 1){ s1 += __shfl_xor(s1, o, 64); s2 += __shfl_xor(s2, o, 64); }
      if (cl == 0){ S1[wav][i*16 + rq*4 + r] = s1; S2[wav][i*16 + rq*4 + r] = s2; }
    }
  __syncthreads();
#pragma unroll
  for (int i = 0; i < 4; ++i)
#pragma unroll
    for (int r = 0; r < 4; ++r) {
      int rr = i*16 + rq*4 + r;
      float t1 = S1[0][rr] + S1[1][rr] + S1[2][rr] + S1[3][rr];
      float t2 = S2[0][rr] + S2[1][rr] + S2[2][rr] + S2[3][rr];
      float mu = t1 * (1.f/256.f);
      float var = t2 * (1.f/256.f) - mu*mu;
      float rs = rsqrtf(fmaxf(var, 0.f) + LEPS);
      int gm = bm + i*16 + rq*4 + r;
      if (gm < M) {
#pragma unroll
        for (int j = 0; j < 4; ++j) {
          int n = wav*64 + j*16 + cl;
          st1(Cln + (size_t)gm*DD + n, (acc[i][j][r] - mu) * rs * lg[n] + lb[n]);
        }
      }
    }
}

// ---- edge K+V GEMM: A = src_h∘h_e (K=256), dual B, += KN/VN[src] (bf16), CSR-slot bf16 out
// NE % 64 == 0: no row guards needed.
template<typename AT>
__global__ __launch_bounds__(256, 2)
void gemm_kve_k(const AT* __restrict__ p0, const AT* __restrict__ p1,
                const int* __restrict__ srcI,
                const US* __restrict__ BpK, const US* __restrict__ BpV,
                const US* __restrict__ KN, const US* __restrict__ VN,
                const int* __restrict__ eperm,
                US* __restrict__ Km, US* __restrict__ Vm)
{
  __shared__ __align__(16) US Alds[64][40];
  __shared__ __align__(16) US BldsK[8192];
  __shared__ __align__(16) US BldsV[8192];
  const int tid  = threadIdx.x;
  const int lane = tid & 63;
  const int wav  = tid >> 6;
  const int bm   = blockIdx.x * 64;

  floatx4 accK[4][4], accV[4][4];
#pragma unroll
  for (int i = 0; i < 4; ++i)
#pragma unroll
    for (int j = 0; j < 4; ++j){ accK[i][j] = (floatx4){0.f,0.f,0.f,0.f}; accV[i][j] = (floatx4){0.f,0.f,0.f,0.f}; }

  const int ar = tid >> 2;
  const int ak = (tid & 3) << 3;
  const int grow = bm + ar;
  const int s = srcI[grow];
  const AT* rA = p0 + (size_t)s * DD;
  const AT* rB = p1 + (size_t)grow * DD;
  const int rq = lane >> 4;
  const int cl = lane & 15;

  for (int k0 = 0; k0 < 256; k0 += 32) {
    const int kk = k0 + ak;
    float av[8], bv[8];
    ld8(rA + kk, av); ld8(rB + kk, bv);
    float mv[8];
#pragma unroll
    for (int j = 0; j < 8; ++j) mv[j] = av[j] * bv[j];
    *(uint4*)&Alds[ar][ak] = pack8(mv);

    const uint4* bsK = (const uint4*)(BpK + (size_t)(k0 >> 3) * 2048);
    const uint4* bsV = (const uint4*)(BpV + (size_t)(k0 >> 3) * 2048);
    uint4* bdK = (uint4*)BldsK; uint4* bdV = (uint4*)BldsV;
#pragma unroll
    for (int u = 0; u < 4; ++u){ bdK[tid + u*256] = bsK[tid + u*256]; bdV[tid + u*256] = bsV[tid + u*256]; }
    __syncthreads();

    short8v af[4], bK4[4], bV4[4];
#pragma unroll
    for (int i = 0; i < 4; ++i) af[i] = *(const short8v*)&Alds[i*16 + cl][rq*8];
#pragma unroll
    for (int j = 0; j < 4; ++j){
      size_t bi = (size_t)(rq*256 + wav*64 + j*16 + cl) * 8;
      bK4[j] = *(const short8v*)&BldsK[bi];
      bV4[j] = *(const short8v*)&BldsV[bi];
    }
#pragma unroll
    for (int i = 0; i < 4; ++i)
#pragma unroll
      for (int j = 0; j < 4; ++j){
        accK[i][j] = __builtin_amdgcn_mfma_f32_16x16x32_bf16(af[i], bK4[j], accK[i][j], 0, 0, 0);
        accV[i][j] = __builtin_amdgcn_mfma_f32_16x16x32_bf16(af[i], bV4[j], accV[i][j], 0, 0, 0);
      }
    __syncthreads();
  }

#pragma unroll
  for (int i = 0; i < 4; ++i)
#pragma unroll
    for (int r = 0; r < 4; ++r) {
      int gm = bm + i*16 + rq*4 + r;
      int pg = eperm[gm];
      int sg = srcI[gm];
      const US* kn = KN + (size_t)sg * DD;
      const US* vn = VN + (size_t)sg * DD;
#pragma unroll
      for (int j = 0; j < 4; ++j) {
        int n = wav*64 + j*16 + cl;
        Km[(size_t)pg*DD + n] = f2bf(accK[i][j][r] + bf2f(kn[n]));
        Vm[(size_t)pg*DD + n] = f2bf(accV[i][j][r] + bf2f(vn[n]));
      }
    }
}

// ---- edge E GEMM: A = h_e (K=256 stream), += EN1[src]+EN2[dst] (bf16), relu+LN -> OT
// NE % 64 == 0: no row guards needed.
template<typename AT, typename OT>
__global__ __launch_bounds__(256, 2)
void gemm_e_k(const AT* __restrict__ he, const int* __restrict__ srcI,
              const int* __restrict__ dstI, const US* __restrict__ Bp,
              const US* __restrict__ EN1, const US* __restrict__ EN2,
              const float* __restrict__ lg, const float* __restrict__ lb,
              OT* __restrict__ Cln)
{
  __shared__ __align__(16) US Alds[64][40];
  __shared__ __align__(16) US Blds[8192];
  __shared__ float S1[4][64], S2[4][64];
  const int tid  = threadIdx.x;
  const int lane = tid & 63;
  const int wav  = tid >> 6;
  const int bm   = blockIdx.x * 64;

  floatx4 acc[4][4];
#pragma unroll
  for (int i = 0; i < 4; ++i)
#pragma unroll
    for (int j = 0; j < 4; ++j) acc[i][j] = (floatx4){0.f,0.f,0.f,0.f};

  const int ar = tid >> 2;
  const int ak = (tid & 3) << 3;
  const int grow = bm + ar;
  const AT* rA = he + (size_t)grow * DD;
  const int rq = lane >> 4;
  const int cl = lane & 15;

  for (int k0 = 0; k0 < 256; k0 += 32) {
    float av[8]; ld8(rA + k0 + ak, av);
    *(uint4*)&Alds[ar][ak] = pack8(av);

    const uint4* bsrc = (const uint4*)(Bp + (size_t)(k0 >> 3) * 2048);
    uint4* bdst = (uint4*)Blds;
#pragma unroll
    for (int u = 0; u < 4; ++u) bdst[tid + u*256] = bsrc[tid + u*256];
    __syncthreads();

    short8v af[4], bfr[4];
#pragma unroll
    for (int i = 0; i < 4; ++i) af[i] = *(const short8v*)&Alds[i*16 + cl][rq*8];
#pragma unroll
    for (int j = 0; j < 4; ++j) bfr[j] = *(const short8v*)&Blds[(size_t)(rq*256 + wav*64 + j*16 + cl) * 8];
#pragma unroll
    for (int i = 0; i < 4; ++i)
#pragma unroll
      for (int j = 0; j < 4; ++j)
        acc[i][j] = __builtin_amdgcn_mfma_f32_16x16x32_bf16(af[i], bfr[j], acc[i][j], 0, 0, 0);
    __syncthreads();
  }

#pragma unroll
  for (int i = 0; i < 4; ++i)
#pragma unroll
    for (int r = 0; r < 4; ++r) {
      int gm = bm + i*16 + rq*4 + r;
      const US* e1 = EN1 + (size_t)srcI[gm] * DD;
      const US* e2 = EN2 + (size_t)dstI[gm] * DD;
#pragma unroll
      for (int j = 0; j < 4; ++j) {
        int n = wav*64 + j*16 + cl;
        float val = acc[i][j][r] + bf2f(e1[n]) + bf2f(e2[n]);
        acc[i][j][r] = fmaxf(val, 0.f);
      }
    }
#pragma unroll
  for (int i = 0; i < 4; ++i)
#pragma unroll
    for (int r = 0; r < 4; ++r) {
      float s1 = 0.f, s2 = 0.f;
#pragma unroll
      for (int j = 0; j < 4; ++j){ float v = acc[i][j][r]; s1 += v; s2 += v*v; }
#pragma unroll
      for (int o = 1; o < 16; o <<= 1){ s1 += __shfl_xor(s1, o, 64); s2 += __shfl_xor(s2, o, 64); }
      if (cl == 0){ S1[wav][i*16 + rq*4 + r] = s1; S2[wav][i*16 + rq*4 + r] = s2; }
    }
  __syncthreads();
#pragma unroll
  for (int i = 0; i < 4; ++i)
#pragma unroll
    for (int r = 0; r < 4; ++r) {
      int rr = i*16 + rq*4 + r;
      float t1 = S1[0][rr] + S1[1][rr] + S1[2][rr] + S1[3][rr];
      float t2 = S2[0][rr] + S2[1][rr] + S2[2][rr] + S2[3][rr];
      float mu = t1 * (1.f/256.f);
      float var = t2 * (1.f/256.f) - mu*mu;
      float rs = rsqrtf(fmaxf(var, 0.f) + LEPS);
      int gm = bm + i*16 + rq*4 + r;
#pragma unroll
      for (int j = 0; j < 4; ++j) {
        int n = wav*64 + j*16 + cl;
        st1(Cln + (size_t)gm*DD + n, (acc[i][j][r] - mu) * rs * lg[n] + lb[n]);
      }
    }
}

// ---- CSR build over dst (emits edge->slot permutation)
__global__ void count_k(const int* __restrict__ key, int* __restrict__ cnt, int e){
  int i = blockIdx.x * blockDim.x + threadIdx.x;
  if (i < e) atomicAdd(&cnt[key[i]], 1);
}
__global__ void scan_k(const int* __restrict__ cnt, int* __restrict__ rp, int n){
  __shared__ int part[256];
  const int t = threadIdx.x;
  const int chunk = (n + 255) / 256;
  int lo = t * chunk, hi = lo + chunk; if (hi > n) hi = n; if (lo > n) lo = n;
  int s = 0;
  for (int i = lo; i < hi; ++i) s += cnt[i];
  part[t] = s; __syncthreads();
  if (t == 0){ int run = 0; for (int i = 0; i < 256; ++i){ int tmp = part[i]; part[i] = run; run += tmp; } rp[n] = run; }
  __syncthreads();
  int run = part[t];
  for (int i = lo; i < hi; ++i){ rp[i] = run; run += cnt[i]; }
}
__global__ void scatter_k(const int* __restrict__ key, const int* __restrict__ rp,
                          int* __restrict__ pos, int* __restrict__ eperm, int e){
  int i = blockIdx.x * blockDim.x + threadIdx.x;
  if (i >= e) return;
  int d = key[i];
  int p = atomicAdd(&pos[d], 1);
  eperm[i] = rp[d] + p;
}

// ---- per-node online softmax + aggregation; K/V in CSR order -> sequential reads
__global__ __launch_bounds__(256)
void node_agg_k(const int* __restrict__ rp,
                const US* __restrict__ Q, const US* __restrict__ Km,
                const US* __restrict__ Vm, float* __restrict__ agg)
{
  int d = blockIdx.x, f = threadIdx.x;
  int beg = rp[d], end = rp[d + 1];
  float q = bf2f(Q[(size_t)d * DD + f]);
  float m = -3.0e38f, z = 0.f, s = 0.f;
  for (int i = beg; i < end; ++i){
    float a  = q * bf2f(Km[(size_t)i * DD + f]);
    float vv = bf2f(Vm[(size_t)i * DD + f]);
    float mn = fmaxf(m, a);
    float sc = __expf(m - mn);
    float w  = __expf(a - mn);
    z = z * sc + w;
    s = s * sc + w * vv;
    m = mn;
  }
  agg[(size_t)d * DD + f] = (z > 0.f) ? (s / z) : 0.f;
}

__global__ void sentinel_k(int hostbits, float* out){
  int code = 0;
  if (hostbits & 1) code = 1;
  else if (hostbits & 2) code = 2;
  else if (hostbits & 4) code = 3;
  else if (hostbits & 8) code = 4;
  if (code) out[0] = (float)code * 1.0e6f;
}

// ---------------- per-layer driver ----------------
struct Bufs {
  float *agg, *hn_new;
  US *QN, *KN, *VN, *EN1, *EN2, *Kmat, *Vmat, *arena;
  int *rp, *eperm;
  const int *src, *dst;
  const float *lg, *lb;
};
template<typename AT, typename OT>
static void layer_run(const Bufs& B, const AT* hn_in, const AT* he_in,
                      OT* hn_out, OT* he_out,
                      const float* Kb, const float* Vb, const float* Qb,
                      const float* Wb, const float* Eb, hipStream_t stream)
{
  const int gN = (NN + 63) / 64, gE = NE / 64;
  gemm_nmulti_k<AT, US><<<dim3(gN, 3), 256, 0, stream>>>(hn_in,
      B.arena + AOFF_Q, Qb, B.QN,
      B.arena + AOFF_K2, Kb, B.KN,
      B.arena + AOFF_V2, Vb, B.VN, NN);
  gemm_kve_k<AT><<<gE, 256, 0, stream>>>(hn_in, he_in, B.src,
      B.arena + AOFF_K1, B.arena + AOFF_V1, B.KN, B.VN, B.eperm, B.Kmat, B.Vmat);
  node_agg_k<<<NN, 256, 0, stream>>>(B.rp, B.QN, B.Kmat, B.Vmat, B.agg);
  gemm_w_k<AT, OT><<<gN, 256, 0, stream>>>(B.agg, hn_in, B.arena + AOFF_W, Wb,
      B.lg, B.lb, B.hn_new, hn_out, NN);
  gemm_nmulti_k<float, US><<<dim3(gN, 2), 256, 0, stream>>>(B.hn_new,
      B.arena + AOFF_E1, Eb, B.EN1,  B.arena + AOFF_E2, nullptr, B.EN2,
      B.arena + AOFF_E2, nullptr, B.EN2, NN);
  gemm_e_k<AT, OT><<<gE, 256, 0, stream>>>(he_in, B.src, B.dst, B.arena + AOFF_E3,
      B.EN1, B.EN2, B.lg, B.lb, he_out);
}

extern "C" void kernel_launch(void* const* d_in, const int* in_sizes, int n_in,
                              void* d_out, int out_size, void* d_ws, size_t ws_size,
                              hipStream_t stream) {
  const float* node_h = (const float*)d_in[0];
  const float* edge_h = (const float*)d_in[1];
  const int*   src    = (const int*)d_in[2];
  const int*   dst    = (const int*)d_in[3];
  const float* Kw = (const float*)d_in[4];  const float* Kb = (const float*)d_in[5];
  const float* Vw = (const float*)d_in[6];  const float* Vb = (const float*)d_in[7];
  const float* Qw = (const float*)d_in[8];  const float* Qb = (const float*)d_in[9];
  const float* Ww = (const float*)d_in[10]; const float* Wb = (const float*)d_in[11];
  const float* Ew = (const float*)d_in[12]; const float* Eb = (const float*)d_in[13];
  const float* ln_g = (const float*)d_in[14];
  const float* ln_b = (const float*)d_in[15];

  char* w = (char*)d_ws; size_t off = 0;
  auto alloc = [&](size_t bytes)->char* {
    char* p = w + off; off += (bytes + 255) & ~(size_t)255; return p;
  };
  float* agg    = (float*)alloc((size_t)NN * DD * 4);
  float* hn_new = (float*)alloc((size_t)NN * DD * 4);
  US* QN     = (US*)alloc((size_t)NN * DD * 2);
  US* hn_cur = (US*)alloc((size_t)NN * DD * 2);
  US* KN     = (US*)alloc((size_t)NN * DD * 2);
  US* VN     = (US*)alloc((size_t)NN * DD * 2);
  US* EN1    = (US*)alloc((size_t)NN * DD * 2);
  US* EN2    = (US*)alloc((size_t)NN * DD * 2);
  US* Kmat   = (US*)alloc((size_t)NE * DD * 2);
  US* Vmat   = (US*)alloc((size_t)NE * DD * 2);
  US* he_cur = (US*)alloc((size_t)NE * DD * 2);
  US* arena  = (US*)alloc((size_t)320 * 2048 * 2);
  int* cnt   = (int*)alloc((size_t)NN * 4);
  int* rp    = (int*)alloc((size_t)(NN + 1) * 4);
  int* pos   = (int*)alloc((size_t)NN * 4);
  int* eperm = (int*)alloc((size_t)NE * 4);

  float* out_hn = (float*)d_out;
  float* out_he = out_hn + (size_t)NN * DD;

  int hostbits = 0;
  {
    static const int exp_sizes[16] = {NN*DD, NE*DD, NE, NE, 2*512*DD, 2*DD, 2*512*DD, 2*DD,
                                      2*DD*DD, 2*DD, 2*512*DD, 2*DD, 2*768*DD, 2*DD, DD, DD};
    if (n_in != 16) hostbits |= 2;
    else { for (int i = 0; i < 16; ++i) if (in_sizes[i] != exp_sizes[i]) hostbits |= 2; }
    if (out_size != NN*DD + NE*DD) hostbits |= 4;
    if (off > ws_size) hostbits |= 1;
  }
  if (hostbits) {
    sentinel_k<<<1, 1, 0, stream>>>(hostbits, out_hn);
    return;
  }

  // CSR over dst (shared by both layers)
  hipMemsetAsync(cnt, 0, (size_t)NN * 4, stream);
  hipMemsetAsync(pos, 0, (size_t)NN * 4, stream);
  count_k<<<(NE + 255)/256, 256, 0, stream>>>(dst, cnt, NE);
  scan_k<<<1, 256, 0, stream>>>(cnt, rp, NN);
  scatter_k<<<(NE + 255)/256, 256, 0, stream>>>(dst, rp, pos, eperm, NE);

  Bufs B{agg, hn_new, QN, KN, VN, EN1, EN2, Kmat, Vmat, arena, rp, eperm,
         src, dst, ln_g, ln_b};

  // layer 0: f32 inputs -> bf16 hn_cur/he_cur
  pack_all_k<<<320, 256, 0, stream>>>(Qw, Kw, Vw, Ww, Ew, arena);
  layer_run<float, US>(B, node_h, edge_h, hn_cur, he_cur,
                       Kb, Vb, Qb, Wb, Eb, stream);
  // layer 1: bf16 inputs -> f32 d_out
  pack_all_k<<<320, 256, 0, stream>>>(Qw + (size_t)256*DD, Kw + (size_t)512*DD,
                                      Vw + (size_t)512*DD, Ww + (size_t)512*DD,
                                      Ew + (size_t)768*DD, arena);
  layer_run<US, float>(B, hn_cur, he_cur, out_hn, out_he,
                       Kb + DD, Vb + DD, Qb + DD, Wb + DD, Eb + DD, stream);

  if (hipGetLastError() != hipSuccess) {
    sentinel_k<<<1, 1, 0, stream>>>(8, out_hn);
  }
}

// Round 20
// 772.856 us; speedup vs baseline: 1.2040x; 1.0173x over previous
//
#include <hip/hip_runtime.h>

#define NN 10000
#define NE 160000
#define DD 256
#define LEPS 1e-5f

typedef __attribute__((ext_vector_type(8))) short short8v;
typedef __attribute__((ext_vector_type(4))) float floatx4;
typedef unsigned short US;

static __device__ __forceinline__ US f2bf(float f){
  unsigned u = __builtin_bit_cast(unsigned, f);
  u += 0x7FFFu + ((u >> 16) & 1u);
  return (US)(u >> 16);
}
static __device__ __forceinline__ float bf2f(US s){
  unsigned u = ((unsigned)s) << 16;
  return __builtin_bit_cast(float, u);
}
template<typename T>
static __device__ __forceinline__ void ld8(const T* p, float* o){
  if constexpr (sizeof(T) == 2) {
    union { US h[8]; uint4 q; } u;
    u.q = *(const uint4*)p;
#pragma unroll
    for (int j = 0; j < 8; ++j) o[j] = bf2f(u.h[j]);
  } else {
    float4 a = *(const float4*)p; float4 b = *(const float4*)(p + 4);
    o[0]=a.x; o[1]=a.y; o[2]=a.z; o[3]=a.w; o[4]=b.x; o[5]=b.y; o[6]=b.z; o[7]=b.w;
  }
}
template<typename OT>
static __device__ __forceinline__ void st1(OT* p, float v){
  if constexpr (sizeof(OT) == 2) *p = (OT)f2bf(v); else *p = (OT)v;
}
static __device__ __forceinline__ uint4 pack8(const float* a){
  union { US h[8]; uint4 q; } pk;
#pragma unroll
  for (int j = 0; j < 8; ++j) pk.h[j] = f2bf(a[j]);
  return pk.q;
}
// async global->LDS, 16B/lane; dest linear base + lane*16 (ours is)
static __device__ __forceinline__ void gl_lds16(const US* g, US* l){
  __builtin_amdgcn_global_load_lds((const __attribute__((address_space(1))) unsigned int*)g,
                                   (__attribute__((address_space(3))) unsigned int*)l, 16, 0, 0);
}

// ---- pack ALL layer weights into fragment-ready arena (kb-blocks of 2048 US)
#define AOFF_Q  0
#define AOFF_K1 (32*2048)
#define AOFF_K2 (64*2048)
#define AOFF_V1 (96*2048)
#define AOFF_V2 (128*2048)
#define AOFF_W  (160*2048)
#define AOFF_E1 (224*2048)
#define AOFF_E2 (256*2048)
#define AOFF_E3 (288*2048)
__global__ void pack_all_k(const float* __restrict__ Qw, const float* __restrict__ Kw,
                           const float* __restrict__ Vw, const float* __restrict__ Ww,
                           const float* __restrict__ Ew, US* __restrict__ arena){
  int i = blockIdx.x * 256 + threadIdx.x;
  int g = i >> 8, n = i & 255;
  const float* src; int row0;
  if      (g <  32){ src = Qw; row0 = g*8; }
  else if (g <  64){ src = Kw; row0 = (g-32)*8; }
  else if (g <  96){ src = Kw; row0 = 256 + (g-64)*8; }
  else if (g < 128){ src = Vw; row0 = (g-96)*8; }
  else if (g < 160){ src = Vw; row0 = 256 + (g-128)*8; }
  else if (g < 224){ src = Ww; row0 = (g-160)*8; }
  else if (g < 256){ src = Ew; row0 = (g-224)*8; }
  else if (g < 288){ src = Ew; row0 = 256 + (g-256)*8; }
  else             { src = Ew; row0 = 512 + (g-288)*8; }
  union { US h[8]; uint4 q; } pk;
#pragma unroll
  for (int j = 0; j < 8; ++j) pk.h[j] = f2bf(src[(size_t)(row0 + j)*DD + n]);
  *(uint4*)(arena + (size_t)g*2048 + n*8) = pk.q;
}

// ---- multi-output node GEMM: C_y = A[M][256] @ B_y + bias_y ; y = blockIdx.y
template<typename AT, typename OT>
__global__ __launch_bounds__(256, 2)
void gemm_nmulti_k(const AT* __restrict__ p0,
                   const US* bp0, const float* b0, OT* o0,
                   const US* bp1, const float* b1, OT* o1,
                   const US* bp2, const float* b2, OT* o2, int M)
{
  const US* Bp  = (blockIdx.y == 0) ? bp0 : (blockIdx.y == 1 ? bp1 : bp2);
  const float* bias = (blockIdx.y == 0) ? b0 : (blockIdx.y == 1 ? b1 : b2);
  OT* out = (blockIdx.y == 0) ? o0 : (blockIdx.y == 1 ? o1 : o2);
  __shared__ __align__(16) US Alds[64][40];
  __shared__ __align__(16) US Blds[8192];
  const int tid  = threadIdx.x;
  const int lane = tid & 63;
  const int wav  = tid >> 6;
  const int bm   = blockIdx.x * 64;

  floatx4 acc[4][4];
#pragma unroll
  for (int i = 0; i < 4; ++i)
#pragma unroll
    for (int j = 0; j < 4; ++j) acc[i][j] = (floatx4){0.f,0.f,0.f,0.f};

  const int ar = tid >> 2;
  const int ak = (tid & 3) << 3;
  int grow = bm + ar; if (grow > M - 1) grow = M - 1;
  const AT* rA = p0 + (size_t)grow * DD;
  const int rq = lane >> 4;
  const int cl = lane & 15;

  for (int k0 = 0; k0 < 256; k0 += 32) {
#pragma unroll
    for (int u = 0; u < 4; ++u)
      gl_lds16(Bp + (size_t)(k0 >> 3) * 2048 + (size_t)(tid + u*256)*8,
               Blds + (size_t)(tid + u*256)*8);
    float av[8]; ld8(rA + k0 + ak, av);
    *(uint4*)&Alds[ar][ak] = pack8(av);
    __syncthreads();

    short8v af[4], bfr[4];
#pragma unroll
    for (int i = 0; i < 4; ++i) af[i] = *(const short8v*)&Alds[i*16 + cl][rq*8];
#pragma unroll
    for (int j = 0; j < 4; ++j) bfr[j] = *(const short8v*)&Blds[(size_t)(rq*256 + wav*64 + j*16 + cl) * 8];
#pragma unroll
    for (int i = 0; i < 4; ++i)
#pragma unroll
      for (int j = 0; j < 4; ++j)
        acc[i][j] = __builtin_amdgcn_mfma_f32_16x16x32_bf16(af[i], bfr[j], acc[i][j], 0, 0, 0);
    __syncthreads();
  }

#pragma unroll
  for (int i = 0; i < 4; ++i)
#pragma unroll
    for (int r = 0; r < 4; ++r) {
      int gm = bm + i*16 + rq*4 + r;
      if (gm < M) {
#pragma unroll
        for (int j = 0; j < 4; ++j) {
          int n = wav*64 + j*16 + cl;
          float b = bias ? bias[n] : 0.f;
          st1(out + (size_t)gm*DD + n, acc[i][j][r] + b);
        }
      }
    }
}

// ---- W GEMM: A=[agg(f32), hn(AT)] K=512 -> raw f32 + LN(OT)
template<typename AT, typename OT>
__global__ __launch_bounds__(256, 2)
void gemm_w_k(const float* __restrict__ p0, const AT* __restrict__ p1,
              const US* __restrict__ Bp, const float* __restrict__ bias,
              const float* __restrict__ lg, const float* __restrict__ lb,
              float* __restrict__ Craw, OT* __restrict__ Cln, int M)
{
  __shared__ __align__(16) US Alds[64][40];
  __shared__ __align__(16) US Blds[8192];
  __shared__ float S1[4][64], S2[4][64];
  const int tid  = threadIdx.x;
  const int lane = tid & 63;
  const int wav  = tid >> 6;
  const int bm   = blockIdx.x * 64;

  floatx4 acc[4][4];
#pragma unroll
  for (int i = 0; i < 4; ++i)
#pragma unroll
    for (int j = 0; j < 4; ++j) acc[i][j] = (floatx4){0.f,0.f,0.f,0.f};

  const int ar = tid >> 2;
  const int ak = (tid & 3) << 3;
  int grow = bm + ar; if (grow > M - 1) grow = M - 1;
  const float* rA = p0 + (size_t)grow * DD;
  const AT*    rB = p1 + (size_t)grow * DD;
  const int rq = lane >> 4;
  const int cl = lane & 15;

  for (int k0 = 0; k0 < 512; k0 += 32) {
#pragma unroll
    for (int u = 0; u < 4; ++u)
      gl_lds16(Bp + (size_t)(k0 >> 3) * 2048 + (size_t)(tid + u*256)*8,
               Blds + (size_t)(tid + u*256)*8);
    const int kk = k0 + ak;
    float av[8];
    if (kk < DD) ld8(rA + kk, av); else ld8(rB + kk - DD, av);
    *(uint4*)&Alds[ar][ak] = pack8(av);
    __syncthreads();

    short8v af[4], bfr[4];
#pragma unroll
    for (int i = 0; i < 4; ++i) af[i] = *(const short8v*)&Alds[i*16 + cl][rq*8];
#pragma unroll
    for (int j = 0; j < 4; ++j) bfr[j] = *(const short8v*)&Blds[(size_t)(rq*256 + wav*64 + j*16 + cl) * 8];
#pragma unroll
    for (int i = 0; i < 4; ++i)
#pragma unroll
      for (int j = 0; j < 4; ++j)
        acc[i][j] = __builtin_amdgcn_mfma_f32_16x16x32_bf16(af[i], bfr[j], acc[i][j], 0, 0, 0);
    __syncthreads();
  }

#pragma unroll
  for (int i = 0; i < 4; ++i)
#pragma unroll
    for (int j = 0; j < 4; ++j) {
      int n = wav*64 + j*16 + cl;
      float bs = bias[n];
#pragma unroll
      for (int r = 0; r < 4; ++r) {
        int gm = bm + i*16 + rq*4 + r;
        float val = acc[i][j][r] + bs;
        if (gm < M) Craw[(size_t)gm*DD + n] = val;
        acc[i][j][r] = fmaxf(val, 0.f);
      }
    }
#pragma unroll
  for (int i = 0; i < 4; ++i)
#pragma unroll
    for (int r = 0; r < 4; ++r) {
      float s1 = 0.f, s2 = 0.f;
#pragma unroll
      for (int j = 0; j < 4; ++j){ float v = acc[i][j][r]; s1 += v; s2 += v*v; }
#pragma unroll
      for (int o = 1; o < 16; o <<= 1){ s1 += __shfl_xor(s1, o, 64); s2 += __shfl_xor(s2, o, 64); }
      if (cl == 0){ S1[wav][i*16 + rq*4 + r] = s1; S2[wav][i*16 + rq*4 + r] = s2; }
    }
  __syncthreads();
#pragma unroll
  for (int i = 0; i < 4; ++i)
#pragma unroll
    for (int r = 0; r < 4; ++r) {
      int rr = i*16 + rq*4 + r;
      float t1 = S1[0][rr] + S1[1][rr] + S1[2][rr] + S1[3][rr];
      float t2 = S2[0][rr] + S2[1][rr] + S2[2][rr] + S2[3][rr];
      float mu = t1 * (1.f/256.f);
      float var = t2 * (1.f/256.f) - mu*mu;
      float rs = rsqrtf(fmaxf(var, 0.f) + LEPS);
      int gm = bm + i*16 + rq*4 + r;
      if (gm < M) {
#pragma unroll
        for (int j = 0; j < 4; ++j) {
          int n = wav*64 + j*16 + cl;
          st1(Cln + (size_t)gm*DD + n, (acc[i][j][r] - mu) * rs * lg[n] + lb[n]);
        }
      }
    }
}

// ---- edge K+V GEMM: A = src_h∘h_e (K=256), dual B, += KN/VN[src] (bf16), CSR-slot bf16 out
template<typename AT>
__global__ __launch_bounds__(256, 2)
void gemm_kve_k(const AT* __restrict__ p0, const AT* __restrict__ p1,
                const int* __restrict__ srcI,
                const US* __restrict__ BpK, const US* __restrict__ BpV,
                const US* __restrict__ KN, const US* __restrict__ VN,
                const int* __restrict__ eperm,
                US* __restrict__ Km, US* __restrict__ Vm)
{
  __shared__ __align__(16) US Alds[64][40];
  __shared__ __align__(16) US BldsK[8192];
  __shared__ __align__(16) US BldsV[8192];
  const int tid  = threadIdx.x;
  const int lane = tid & 63;
  const int wav  = tid >> 6;
  const int bm   = blockIdx.x * 64;

  floatx4 accK[4][4], accV[4][4];
#pragma unroll
  for (int i = 0; i < 4; ++i)
#pragma unroll
    for (int j = 0; j < 4; ++j){ accK[i][j] = (floatx4){0.f,0.f,0.f,0.f}; accV[i][j] = (floatx4){0.f,0.f,0.f,0.f}; }

  const int ar = tid >> 2;
  const int ak = (tid & 3) << 3;
  const int grow = bm + ar;
  const int s = srcI[grow];
  const AT* rA = p0 + (size_t)s * DD;
  const AT* rB = p1 + (size_t)grow * DD;
  const int rq = lane >> 4;
  const int cl = lane & 15;

  for (int k0 = 0; k0 < 256; k0 += 32) {
#pragma unroll
    for (int u = 0; u < 4; ++u){
      gl_lds16(BpK + (size_t)(k0 >> 3) * 2048 + (size_t)(tid + u*256)*8,
               BldsK + (size_t)(tid + u*256)*8);
      gl_lds16(BpV + (size_t)(k0 >> 3) * 2048 + (size_t)(tid + u*256)*8,
               BldsV + (size_t)(tid + u*256)*8);
    }
    const int kk = k0 + ak;
    float av[8], bv[8];
    ld8(rA + kk, av); ld8(rB + kk, bv);
    float mv[8];
#pragma unroll
    for (int j = 0; j < 8; ++j) mv[j] = av[j] * bv[j];
    *(uint4*)&Alds[ar][ak] = pack8(mv);
    __syncthreads();

    short8v af[4], bK4[4], bV4[4];
#pragma unroll
    for (int i = 0; i < 4; ++i) af[i] = *(const short8v*)&Alds[i*16 + cl][rq*8];
#pragma unroll
    for (int j = 0; j < 4; ++j){
      size_t bi = (size_t)(rq*256 + wav*64 + j*16 + cl) * 8;
      bK4[j] = *(const short8v*)&BldsK[bi];
      bV4[j] = *(const short8v*)&BldsV[bi];
    }
#pragma unroll
    for (int i = 0; i < 4; ++i)
#pragma unroll
      for (int j = 0; j < 4; ++j){
        accK[i][j] = __builtin_amdgcn_mfma_f32_16x16x32_bf16(af[i], bK4[j], accK[i][j], 0, 0, 0);
        accV[i][j] = __builtin_amdgcn_mfma_f32_16x16x32_bf16(af[i], bV4[j], accV[i][j], 0, 0, 0);
      }
    __syncthreads();
  }

#pragma unroll
  for (int i = 0; i < 4; ++i)
#pragma unroll
    for (int r = 0; r < 4; ++r) {
      int gm = bm + i*16 + rq*4 + r;
      int pg = eperm[gm];
      int sg = srcI[gm];
      const US* kn = KN + (size_t)sg * DD;
      const US* vn = VN + (size_t)sg * DD;
#pragma unroll
      for (int j = 0; j < 4; ++j) {
        int n = wav*64 + j*16 + cl;
        Km[(size_t)pg*DD + n] = f2bf(accK[i][j][r] + bf2f(kn[n]));
        Vm[(size_t)pg*DD + n] = f2bf(accV[i][j][r] + bf2f(vn[n]));
      }
    }
}

// ---- edge E GEMM: A = h_e (K=256 stream), += EN1[src]+EN2[dst] (bf16), relu+LN -> OT
template<typename AT, typename OT>
__global__ __launch_bounds__(256, 2)
void gemm_e_k(const AT* __restrict__ he, const int* __restrict__ srcI,
              const int* __restrict__ dstI, const US* __restrict__ Bp,
              const US* __restrict__ EN1, const US* __restrict__ EN2,
              const float* __restrict__ lg, const float* __restrict__ lb,
              OT* __restrict__ Cln)
{
  __shared__ __align__(16) US Alds[64][40];
  __shared__ __align__(16) US Blds[8192];
  __shared__ float S1[4][64], S2[4][64];
  const int tid  = threadIdx.x;
  const int lane = tid & 63;
  const int wav  = tid >> 6;
  const int bm   = blockIdx.x * 64;

  floatx4 acc[4][4];
#pragma unroll
  for (int i = 0; i < 4; ++i)
#pragma unroll
    for (int j = 0; j < 4; ++j) acc[i][j] = (floatx4){0.f,0.f,0.f,0.f};

  const int ar = tid >> 2;
  const int ak = (tid & 3) << 3;
  const int grow = bm + ar;
  const AT* rA = he + (size_t)grow * DD;
  const int rq = lane >> 4;
  const int cl = lane & 15;

  for (int k0 = 0; k0 < 256; k0 += 32) {
#pragma unroll
    for (int u = 0; u < 4; ++u)
      gl_lds16(Bp + (size_t)(k0 >> 3) * 2048 + (size_t)(tid + u*256)*8,
               Blds + (size_t)(tid + u*256)*8);
    float av[8]; ld8(rA + k0 + ak, av);
    *(uint4*)&Alds[ar][ak] = pack8(av);
    __syncthreads();

    short8v af[4], bfr[4];
#pragma unroll
    for (int i = 0; i < 4; ++i) af[i] = *(const short8v*)&Alds[i*16 + cl][rq*8];
#pragma unroll
    for (int j = 0; j < 4; ++j) bfr[j] = *(const short8v*)&Blds[(size_t)(rq*256 + wav*64 + j*16 + cl) * 8];
#pragma unroll
    for (int i = 0; i < 4; ++i)
#pragma unroll
      for (int j = 0; j < 4; ++j)
        acc[i][j] = __builtin_amdgcn_mfma_f32_16x16x32_bf16(af[i], bfr[j], acc[i][j], 0, 0, 0);
    __syncthreads();
  }

#pragma unroll
  for (int i = 0; i < 4; ++i)
#pragma unroll
    for (int r = 0; r < 4; ++r) {
      int gm = bm + i*16 + rq*4 + r;
      const US* e1 = EN1 + (size_t)srcI[gm] * DD;
      const US* e2 = EN2 + (size_t)dstI[gm] * DD;
#pragma unroll
      for (int j = 0; j < 4; ++j) {
        int n = wav*64 + j*16 + cl;
        float val = acc[i][j][r] + bf2f(e1[n]) + bf2f(e2[n]);
        acc[i][j][r] = fmaxf(val, 0.f);
      }
    }
#pragma unroll
  for (int i = 0; i < 4; ++i)
#pragma unroll
    for (int r = 0; r < 4; ++r) {
      float s1 = 0.f, s2 = 0.f;
#pragma unroll
      for (int j = 0; j < 4; ++j){ float v = acc[i][j][r]; s1 += v; s2 += v*v; }
#pragma unroll
      for (int o = 1; o < 16; o <<= 1){ s1 += __shfl_xor(s1, o, 64); s2 += __shfl_xor(s2, o, 64); }
      if (cl == 0){ S1[wav][i*16 + rq*4 + r] = s1; S2[wav][i*16 + rq*4 + r] = s2; }
    }
  __syncthreads();
#pragma unroll
  for (int i = 0; i < 4; ++i)
#pragma unroll
    for (int r = 0; r < 4; ++r) {
      int rr = i*16 + rq*4 + r;
      float t1 = S1[0][rr] + S1[1][rr] + S1[2][rr] + S1[3][rr];
      float t2 = S2[0][rr] + S2[1][rr] + S2[2][rr] + S2[3][rr];
      float mu = t1 * (1.f/256.f);
      float var = t2 * (1.f/256.f) - mu*mu;
      float rs = rsqrtf(fmaxf(var, 0.f) + LEPS);
      int gm = bm + i*16 + rq*4 + r;
#pragma unroll
      for (int j = 0; j < 4; ++j) {
        int n = wav*64 + j*16 + cl;
        st1(Cln + (size_t)gm*DD + n, (acc[i][j][r] - mu) * rs * lg[n] + lb[n]);
      }
    }
}

// ---- CSR build over dst (emits edge->slot permutation)
__global__ void count_k(const int* __restrict__ key, int* __restrict__ cnt, int e){
  int i = blockIdx.x * blockDim.x + threadIdx.x;
  if (i < e) atomicAdd(&cnt[key[i]], 1);
}
__global__ void scan_k(const int* __restrict__ cnt, int* __restrict__ rp, int n){
  __shared__ int part[256];
  const int t = threadIdx.x;
  const int chunk = (n + 255) / 256;
  int lo = t * chunk, hi = lo + chunk; if (hi > n) hi = n; if (lo > n) lo = n;
  int s = 0;
  for (int i = lo; i < hi; ++i) s += cnt[i];
  part[t] = s; __syncthreads();
  if (t == 0){ int run = 0; for (int i = 0; i < 256; ++i){ int tmp = part[i]; part[i] = run; run += tmp; } rp[n] = run; }
  __syncthreads();
  int run = part[t];
  for (int i = lo; i < hi; ++i){ rp[i] = run; run += cnt[i]; }
}
__global__ void scatter_k(const int* __restrict__ key, const int* __restrict__ rp,
                          int* __restrict__ pos, int* __restrict__ eperm, int e){
  int i = blockIdx.x * blockDim.x + threadIdx.x;
  if (i >= e) return;
  int d = key[i];
  int p = atomicAdd(&pos[d], 1);
  eperm[i] = rp[d] + p;
}

// ---- per-node online softmax + aggregation; K/V in CSR order -> sequential reads
__global__ __launch_bounds__(256)
void node_agg_k(const int* __restrict__ rp,
                const US* __restrict__ Q, const US* __restrict__ Km,
                const US* __restrict__ Vm, float* __restrict__ agg)
{
  int d = blockIdx.x, f = threadIdx.x;
  int beg = rp[d], end = rp[d + 1];
  float q = bf2f(Q[(size_t)d * DD + f]);
  float m = -3.0e38f, z = 0.f, s = 0.f;
  for (int i = beg; i < end; ++i){
    float a  = q * bf2f(Km[(size_t)i * DD + f]);
    float vv = bf2f(Vm[(size_t)i * DD + f]);
    float mn = fmaxf(m, a);
    float sc = __expf(m - mn);
    float w  = __expf(a - mn);
    z = z * sc + w;
    s = s * sc + w * vv;
    m = mn;
  }
  agg[(size_t)d * DD + f] = (z > 0.f) ? (s / z) : 0.f;
}

__global__ void sentinel_k(int hostbits, float* out){
  int code = 0;
  if (hostbits & 1) code = 1;
  else if (hostbits & 2) code = 2;
  else if (hostbits & 4) code = 3;
  else if (hostbits & 8) code = 4;
  if (code) out[0] = (float)code * 1.0e6f;
}

// ---------------- per-layer driver ----------------
struct Bufs {
  float *agg, *hn_new;
  US *QN, *KN, *VN, *EN1, *EN2, *Kmat, *Vmat, *arena;
  int *rp, *eperm;
  const int *src, *dst;
  const float *lg, *lb;
};
template<typename AT, typename OT>
static void layer_run(const Bufs& B, const AT* hn_in, const AT* he_in,
                      OT* hn_out, OT* he_out,
                      const float* Kb, const float* Vb, const float* Qb,
                      const float* Wb, const float* Eb, hipStream_t stream)
{
  const int gN = (NN + 63) / 64, gE = NE / 64;
  gemm_nmulti_k<AT, US><<<dim3(gN, 3), 256, 0, stream>>>(hn_in,
      B.arena + AOFF_Q, Qb, B.QN,
      B.arena + AOFF_K2, Kb, B.KN,
      B.arena + AOFF_V2, Vb, B.VN, NN);
  gemm_kve_k<AT><<<gE, 256, 0, stream>>>(hn_in, he_in, B.src,
      B.arena + AOFF_K1, B.arena + AOFF_V1, B.KN, B.VN, B.eperm, B.Kmat, B.Vmat);
  node_agg_k<<<NN, 256, 0, stream>>>(B.rp, B.QN, B.Kmat, B.Vmat, B.agg);
  gemm_w_k<AT, OT><<<gN, 256, 0, stream>>>(B.agg, hn_in, B.arena + AOFF_W, Wb,
      B.lg, B.lb, B.hn_new, hn_out, NN);
  gemm_nmulti_k<float, US><<<dim3(gN, 2), 256, 0, stream>>>(B.hn_new,
      B.arena + AOFF_E1, Eb, B.EN1,  B.arena + AOFF_E2, nullptr, B.EN2,
      B.arena + AOFF_E2, nullptr, B.EN2, NN);
  gemm_e_k<AT, OT><<<gE, 256, 0, stream>>>(he_in, B.src, B.dst, B.arena + AOFF_E3,
      B.EN1, B.EN2, B.lg, B.lb, he_out);
}

extern "C" void kernel_launch(void* const* d_in, const int* in_sizes, int n_in,
                              void* d_out, int out_size, void* d_ws, size_t ws_size,
                              hipStream_t stream) {
  const float* node_h = (const float*)d_in[0];
  const float* edge_h = (const float*)d_in[1];
  const int*   src    = (const int*)d_in[2];
  const int*   dst    = (const int*)d_in[3];
  const float* Kw = (const float*)d_in[4];  const float* Kb = (const float*)d_in[5];
  const float* Vw = (const float*)d_in[6];  const float* Vb = (const float*)d_in[7];
  const float* Qw = (const float*)d_in[8];  const float* Qb = (const float*)d_in[9];
  const float* Ww = (const float*)d_in[10]; const float* Wb = (const float*)d_in[11];
  const float* Ew = (const float*)d_in[12]; const float* Eb = (const float*)d_in[13];
  const float* ln_g = (const float*)d_in[14];
  const float* ln_b = (const float*)d_in[15];

  char* w = (char*)d_ws; size_t off = 0;
  auto alloc = [&](size_t bytes)->char* {
    char* p = w + off; off += (bytes + 255) & ~(size_t)255; return p;
  };
  float* agg    = (float*)alloc((size_t)NN * DD * 4);
  float* hn_new = (float*)alloc((size_t)NN * DD * 4);
  US* QN     = (US*)alloc((size_t)NN * DD * 2);
  US* hn_cur = (US*)alloc((size_t)NN * DD * 2);
  US* KN     = (US*)alloc((size_t)NN * DD * 2);
  US* VN     = (US*)alloc((size_t)NN * DD * 2);
  US* EN1    = (US*)alloc((size_t)NN * DD * 2);
  US* EN2    = (US*)alloc((size_t)NN * DD * 2);
  US* Kmat   = (US*)alloc((size_t)NE * DD * 2);
  US* Vmat   = (US*)alloc((size_t)NE * DD * 2);
  US* he_cur = (US*)alloc((size_t)NE * DD * 2);
  US* arena  = (US*)alloc((size_t)320 * 2048 * 2);
  int* cnt   = (int*)alloc((size_t)NN * 4);
  int* rp    = (int*)alloc((size_t)(NN + 1) * 4);
  int* pos   = (int*)alloc((size_t)NN * 4);
  int* eperm = (int*)alloc((size_t)NE * 4);

  float* out_hn = (float*)d_out;
  float* out_he = out_hn + (size_t)NN * DD;

  int hostbits = 0;
  {
    static const int exp_sizes[16] = {NN*DD, NE*DD, NE, NE, 2*512*DD, 2*DD, 2*512*DD, 2*DD,
                                      2*DD*DD, 2*DD, 2*512*DD, 2*DD, 2*768*DD, 2*DD, DD, DD};
    if (n_in != 16) hostbits |= 2;
    else { for (int i = 0; i < 16; ++i) if (in_sizes[i] != exp_sizes[i]) hostbits |= 2; }
    if (out_size != NN*DD + NE*DD) hostbits |= 4;
    if (off > ws_size) hostbits |= 1;
  }
  if (hostbits) {
    sentinel_k<<<1, 1, 0, stream>>>(hostbits, out_hn);
    return;
  }

  // CSR over dst (shared by both layers)
  hipMemsetAsync(cnt, 0, (size_t)NN * 4, stream);
  hipMemsetAsync(pos, 0, (size_t)NN * 4, stream);
  count_k<<<(NE + 255)/256, 256, 0, stream>>>(dst, cnt, NE);
  scan_k<<<1, 256, 0, stream>>>(cnt, rp, NN);
  scatter_k<<<(NE + 255)/256, 256, 0, stream>>>(dst, rp, pos, eperm, NE);

  Bufs B{agg, hn_new, QN, KN, VN, EN1, EN2, Kmat, Vmat, arena, rp, eperm,
         src, dst, ln_g, ln_b};

  // layer 0: f32 inputs -> bf16 hn_cur/he_cur
  pack_all_k<<<320, 256, 0, stream>>>(Qw, Kw, Vw, Ww, Ew, arena);
  layer_run<float, US>(B, node_h, edge_h, hn_cur, he_cur,
                       Kb, Vb, Qb, Wb, Eb, stream);
  // layer 1: bf16 inputs -> f32 d_out
  pack_all_k<<<320, 256, 0, stream>>>(Qw + (size_t)256*DD, Kw + (size_t)512*DD,
                                      Vw + (size_t)512*DD, Ww + (size_t)512*DD,
                                      Ew + (size_t)768*DD, arena);
  layer_run<US, float>(B, hn_cur, he_cur, out_hn, out_he,
                       Kb + DD, Vb + DD, Qb + DD, Wb + DD, Eb + DD, stream);

  if (hipGetLastError() != hipSuccess) {
    sentinel_k<<<1, 1, 0, stream>>>(8, out_hn);
  }
}